// Round 8
// baseline (657.415 us; speedup 1.0000x reference)
//
#include <hip/hip_runtime.h>
#include <cstdint>
#include <cmath>

#pragma clang fp contract(off)

#define N_OBS 2048
#define D_DIM 128
#define R_DIM 16
#define NSAMP 500

// ---- workspace layout (bytes) ----
#define WS_M     0        // 16 f32
#define WS_EY    64       // 128 f32
#define WS_GAIN  576      // 16*128 f32
#define WS_SCAL  8768     // scalars: [0]=trace_C, [1]=pconst, [2]=alpha0
#define WS_G     8800     // 16*16 f32  G = H^T H

// ---- f64-path f32 transcendentals: accept/reject-critical fallbacks only.
__device__ __forceinline__ float flog(float x)   { return (float)log((double)x); }
__device__ __forceinline__ float flog1p(float x) { return (float)log1p((double)x); }

// ---------------- Threefry-2x32, 20 rounds (JAX-compatible) ----------------
__device__ __forceinline__ void tf_block(uint32_t k0, uint32_t k1,
                                         uint32_t x0, uint32_t x1,
                                         uint32_t& o0, uint32_t& o1) {
  const uint32_t k2 = k0 ^ k1 ^ 0x1BD11BDAu;
  x0 += k0; x1 += k1;
#define TF_R(r) { x0 += x1; x1 = (x1 << (r)) | (x1 >> (32 - (r))); x1 ^= x0; }
  TF_R(13) TF_R(15) TF_R(26) TF_R(6)
  x0 += k1; x1 += k2 + 1u;
  TF_R(17) TF_R(29) TF_R(16) TF_R(24)
  x0 += k2; x1 += k0 + 2u;
  TF_R(13) TF_R(15) TF_R(26) TF_R(6)
  x0 += k0; x1 += k1 + 3u;
  TF_R(17) TF_R(29) TF_R(16) TF_R(24)
  x0 += k1; x1 += k2 + 4u;
  TF_R(13) TF_R(15) TF_R(26) TF_R(6)
  x0 += k2; x1 += k0 + 5u;
#undef TF_R
  o0 = x0; o1 = x1;
}

__device__ __forceinline__ uint32_t rb32(uint32_t ka, uint32_t kb) {
  uint32_t o0, o1;
  tf_block(ka, kb, 0u, 0u, o0, o1);
  return o0 ^ o1;
}

__device__ __forceinline__ float u01(uint32_t bits) {
  uint32_t fb = (bits >> 9) | 0x3F800000u;
  return __uint_as_float(fb) - 1.0f;
}

// XLA ErfInv polynomial p(w); x = 1.41421356f * (p * u). Branch on w<5 as in HLO.
__device__ __forceinline__ float erfinv_poly(float w0) {
  float p;
  if (w0 < 5.0f) {
    float w = w0 - 2.5f;
    p = 2.81022636e-08f;
    p = 3.43273939e-07f + p * w;
    p = -3.5233877e-06f + p * w;
    p = -4.39150654e-06f + p * w;
    p = 0.00021858087f + p * w;
    p = -0.00125372503f + p * w;
    p = -0.00417768164f + p * w;
    p = 0.246640727f + p * w;
    p = 1.50140941f + p * w;
  } else {
    float w = sqrtf(w0) - 3.0f;
    p = -0.000200214257f;
    p = 0.000100950558f + p * w;
    p = 0.00134934322f + p * w;
    p = -0.00367342844f + p * w;
    p = 0.00573950773f + p * w;
    p = -0.0076224613f + p * w;
    p = 0.00943887047f + p * w;
    p = 1.00167406f + p * w;
    p = 2.83297682f + p * w;
  }
  return p;
}

// Exact-path normal value from uniform uu (reference-bitwise: f64 log1p)
__device__ __forceinline__ float normal_exact_from_u(float uu) {
  float w = -flog1p(-(uu * uu));
  return 1.41421356f * (erfinv_poly(w) * uu);
}

// ---------------- Kernel 1: LMMSE prep (1 wave, Woodbury 16x16) ----------------
__global__ __launch_bounds__(64) void prep_kernel(const float* __restrict__ H,
                                                  const float* __restrict__ alpha,
                                                  char* __restrict__ ws) {
  float* m    = (float*)(ws + WS_M);
  float* EY   = (float*)(ws + WS_EY);
  float* gain = (float*)(ws + WS_GAIN);
  float* scal = (float*)(ws + WS_SCAL);
  float* Gws  = (float*)(ws + WS_G);

  __shared__ float sH[128 * 16];
  __shared__ float sC[16][16];
  __shared__ float sHC[128 * 16];
  __shared__ float sm[16];
  __shared__ double sHtH[16][16];
  __shared__ double M[16][33];
  __shared__ double dfac[16];
  __shared__ double spiv;
  __shared__ int   spivrow;
  __shared__ float sgain[16 * 128];

  int t = threadIdx.x;
  for (int i = t; i < 2048; i += 64) sH[i] = H[i];
  __syncthreads();

  if (t == 0) {
    float a0 = 0.0f;
    for (int j = 0; j < 16; ++j) a0 += alpha[j];
    float pc = lgammaf(a0);
    for (int j = 0; j < 16; ++j) pc -= lgammaf(alpha[j]);
    scal[2] = a0; scal[1] = pc;
    for (int j = 0; j < 16; ++j) { sm[j] = alpha[j] / a0; m[j] = sm[j]; }
  }
  __syncthreads();
  float a0 = scal[2];

  for (int e = t; e < 256; e += 64) {
    int i = e >> 4, j = e & 15;
    float v = ((i == j) ? sm[i] : 0.0f) - sm[i] * sm[j];
    sC[i][j] = v / (a0 + 1.0f);
  }
  for (int dd = t; dd < 128; dd += 64) {
    float acc = 0.0f;
    for (int j = 0; j < 16; ++j) acc += sH[dd * 16 + j] * sm[j];
    EY[dd] = acc;
  }
  __syncthreads();

  for (int idx = t; idx < 2048; idx += 64) {
    int dd = idx >> 4, j = idx & 15;
    float acc = 0.0f;
    for (int i = 0; i < 16; ++i) acc += sH[dd * 16 + i] * sC[i][j];
    sHC[idx] = acc;
  }
  for (int e = t; e < 256; e += 64) {
    int i = e >> 4, j = e & 15;
    double acc = 0.0;
    for (int dd = 0; dd < 128; ++dd)
      acc += (double)sH[dd * 16 + i] * (double)sH[dd * 16 + j];
    sHtH[i][j] = acc;
    Gws[i * 16 + j] = (float)acc;
  }
  __syncthreads();

  for (int e = t; e < 256; e += 64) {
    int i = e >> 4, j = e & 15;
    double acc = (i == j) ? 0.01 : 0.0;
    for (int k = 0; k < 16; ++k) acc += (double)sC[i][k] * sHtH[k][j];
    M[i][j] = acc;
    M[i][16 + j] = (i == j) ? 1.0 : 0.0;
  }
  __syncthreads();

  for (int p = 0; p < 16; ++p) {
    if (t == 0) {
      int best = p; double bv = fabs(M[p][p]);
      for (int r = p + 1; r < 16; ++r) {
        double v = fabs(M[r][p]);
        if (v > bv) { bv = v; best = r; }
      }
      spivrow = best;
    }
    __syncthreads();
    int pr = spivrow;
    double va = 0.0, vb = 0.0;
    if (t < 32 && pr != p) { va = M[p][t]; vb = M[pr][t]; }
    __syncthreads();
    if (t < 32 && pr != p) { M[p][t] = vb; M[pr][t] = va; }
    __syncthreads();
    if (t == 0) spiv = 1.0 / M[p][p];
    __syncthreads();
    if (t < 32) M[p][t] *= spiv;
    if (t < 16) dfac[t] = M[t][p];
    __syncthreads();
    for (int e = t; e < 512; e += 64) {
      int r = e >> 5, c = e & 31;
      if (r != p) M[r][c] -= dfac[r] * M[p][c];
    }
    __syncthreads();
  }

  for (int idx = t; idx < 2048; idx += 64) {
    int j = idx >> 7, dd = idx & 127;
    double acc = 0.0;
    for (int k = 0; k < 16; ++k) acc += M[j][16 + k] * (double)sHC[dd * 16 + k];
    float g = (float)acc;
    sgain[j * 128 + dd] = g;
    gain[j * 128 + dd] = g;
  }
  __syncthreads();

  if (t == 0) {
    float tr = 0.0f;
    for (int j = 0; j < 16; ++j) {
      float s2 = 0.0f;
      for (int dd = 0; dd < 128; ++dd) s2 += sgain[j * 128 + dd] * sHC[dd * 16 + j];
      tr += sC[j][j] - s2;
    }
    tr = fmaxf(tr, 0.0f) + 1e-6f;
    scal[0] = tr;
  }
}

// ---------------- Kernel 2: fused per-n prep + sampling + moments ----------------
__global__ __launch_bounds__(256) void main_kernel(const float* __restrict__ y,
                                                   const float* __restrict__ Hg,
                                                   const float* __restrict__ alpha,
                                                   const char* __restrict__ ws,
                                                   float* __restrict__ out) {
  const float* mws  = (const float*)(ws + WS_M);
  const float* EYw  = (const float*)(ws + WS_EY);
  const float* gain = (const float*)(ws + WS_GAIN);
  const float* scal = (const float*)(ws + WS_SCAL);
  const float* Gw   = (const float*)(ws + WS_G);

  __shared__ float slg_all[32][256];   // lg for all chunks (32 KB); prologue aliases it
  __shared__ float sz[16][17];
  __shared__ float slw[16], swv[16];
  __shared__ float sdiri[16], su2[16], stv[16];
  __shared__ float smisc[2];           // [0]=cn
  __shared__ float sM, sS, sFac;

  int t = threadIdx.x;
  int n = blockIdx.x;
  int h_sub = t >> 4, j = t & 15;

  // ---- Phase 0: per-n proposal concentrations (bitwise replay of diri_kernel) ----
  {
    float* sGainT = &slg_all[0][0];      // [128][16]: gain transposed
    float* sHs    = sGainT + 2048;       // [128][16]
    float* sys    = sHs + 2048;          // [128]
    float* sEYs   = sys + 128;           // [128]
    for (int i = t; i < 2048; i += 256) {
      sGainT[(i & 127) * 16 + (i >> 7)] = gain[i];   // gain[j*128+dd] -> [dd][j]
      sHs[i] = Hg[i];
    }
    if (t < 128) { sys[t] = y[n * 128 + t]; sEYs[t] = EYw[t]; }
    __syncthreads();
    if (t < 16) {
      float tv = mws[t];
      float u = 0.0f;
      for (int dd = 0; dd < 128; ++dd) {
        float yv = sys[dd];
        float dy = yv - sEYs[dd];
        tv += dy * sGainT[dd * 16 + t];
        u  += yv * sHs[dd * 16 + t];
      }
      stv[t] = tv;
      su2[t] = 2.0f * u;
    }
    __syncthreads();
    if (t == 0) {
      float yy = 0.0f;
      for (int dd = 0; dd < 128; ++dd) yy += sys[dd] * sys[dd];
      float s = 0.0f;
      for (int jj = 0; jj < 16; ++jj) {
        float v = fmaxf(stv[jj], 0.0f) + 1e-6f; stv[jj] = v; s += v;
      }
      float ssq = 0.0f;
      for (int jj = 0; jj < 16; ++jj) {
        float v = stv[jj] / s; stv[jj] = v; ssq += v * v;
      }
      float k = (1.0f - ssq) / scal[0] - 1.0f;
      float dsum = 0.0f, lgs = 0.0f;
      for (int jj = 0; jj < 16; ++jj) {
        float dj = fmaxf(k * stv[jj], 0.0f) + 0.8f;
        sdiri[jj] = dj; dsum += dj; lgs += lgammaf(dj);
      }
      float qcn = lgammaf(dsum) - lgs;
      smisc[0] = scal[1] - qcn - 50.0f * yy;   // lw = -50*(zGz-2zu) + (p2-q) + cn
    }
    __syncthreads();
  }

  float aj   = sdiri[j];
  float uj2  = su2[j];
  float cn   = smisc[0];
  float admj = alpha[j] - aj;

  // ---- Phase 1: self-paced sampling; erfinv + acceptance both margin-gated ----
  {
    bool boost = (aj >= 1.0f);
    float aa = boost ? aj : (aj + 1.0f);
    float d  = aa - 0.33333334f;
    float cc = 0.33333334f / sqrtf(d);
    float inv_a = 1.0f / aj;
    float ld32 = logf(d);
    int numc = (h_sub < 4) ? 32 : 31;        // h = 16c+h_sub < 500
    int c = 0;
    bool need_init = true;
    bool pending = true;
    uint32_t kcx = 0, kcy = 0;
    float log_samples = 0.0f;

    while (__ballot(pending)) {
      if (pending) {
        if (need_init) {
          int h = c * 16 + h_sub;
          uint32_t jf = (((uint32_t)h * 2048u + (uint32_t)n) << 4) | (uint32_t)j;
          uint32_t ka, kb, ska, skb;
          tf_block(0u, 42u, 0u, jf, ka, kb);     // per-sample key (foldlike split)
          tf_block(ka, kb, 0u, 0u, kcx, kcy);    // carried key
          tf_block(ka, kb, 0u, 1u, ska, skb);    // subkey -> exponential
          float ef = u01(rb32(ska, skb));
          log_samples = log1pf(-ef);             // continuous -> f32
          need_init = false;
        }
        // one Marsaglia-Tsang outer iteration
        uint32_t xka, xkb, Uka, Ukb;
        tf_block(kcx, kcy, 0u, 1u, xka, xkb);    // x_key
        tf_block(kcx, kcy, 0u, 2u, Uka, Ukb);    // U_key
        float x = 0.0f, v = -1.0f, ex = 0.0f, uu = 0.0f;
        for (int in = 0; in < 256; ++in) {
          uint32_t sxa, sxb;
          tf_block(xka, xkb, 0u, 1u, sxa, sxb);  // subkey for normal
          float f = u01(rb32(sxa, sxb));
          uu = fmaxf(-0.99999994f, f * 2.0f + (-0.99999994f));
          // fast-path erfinv: f32 log1p + propagated error bound
          float w32 = -log1pf(-(uu * uu));
          if (fabsf(w32 - 5.0f) < 4e-6f) {       // branch straddle -> exact
            x = normal_exact_from_u(uu); ex = 0.0f;
          } else {
            x = 1.41421356f * (erfinv_poly(w32) * uu);
            ex = (w32 < 5.0f) ? (5e-7f * fabsf(uu) * w32 + 1e-9f)
                              : (1e-6f * fabsf(uu) * sqrtf(w32) + 1e-9f);
          }
          v = 1.0f + x * cc;
          if (fabsf(v) <= 2.0f * cc * ex + 1e-9f) {  // v-decision uncertain
            x = normal_exact_from_u(uu); ex = 0.0f;
            v = 1.0f + x * cc;
          }
          if (v > 0.0f) break;
          uint32_t nxa, nxb;
          tf_block(xka, xkb, 0u, 0u, nxa, nxb);  // lazy inner carry
          xka = nxa; xkb = nxb;
        }
        float X = x * x;
        float V = (v * v) * v;
        float U = u01(rb32(Uka, Ukb));
        float lv32 = logf(V);
        bool cont = false;
        bool need_exact = false;
        // squeeze with x-uncertainty gate
        float sqz = 1.0f - 0.0331f * (X * X);
        float ms  = U - sqz;
        float thr_s = 0.3f * fabsf(x) * X * ex + 1e-10f;
        if (fabsf(ms) <= thr_s) {
          need_exact = true;
        } else if (ms < 0.0f) {
          cont = false;                          // U < squeeze -> accept
        } else {
          // margin-gated log test (f32 fast path)
          float lu32  = logf(U);
          float rhs32 = X * 0.5f + d * ((1.0f - V) + lv32);
          float margin = lu32 - rhs32;
          float thr = 4.8e-7f * fabsf(lu32)
                    + 4.8e-7f * d * fabsf(lv32)
                    + 1.2e-7f * (fabsf(rhs32) + X)
                    + 1e-7f
                    + ex * (2.0f * fabsf(x) + 8.0f * d * cc * fabsf(1.0f - V) / v);
          if (fabsf(margin) > thr) cont = (margin >= 0.0f);
          else need_exact = true;
        }
        if (need_exact) {                        // rare: reference-exact replay
          if (ex > 0.0f) {
            x = normal_exact_from_u(uu);
            v = 1.0f + x * cc; X = x * x; V = (v * v) * v;
            lv32 = logf(V);
          }
          cont = (U >= 1.0f - 0.0331f * (X * X));
          if (cont) cont = (flog(U) >= X * 0.5f + d * ((1.0f - V) + flog(V)));
        }
        if (cont) {
          uint32_t kna, knb;
          tf_block(kcx, kcy, 0u, 0u, kna, knb);  // lazy outer carry
          kcx = kna; kcy = knb;
        } else {
          float log_boost = (boost || log_samples == 0.0f)
                              ? 0.0f : log_samples * inv_a;
          slg_all[c][t] = (ld32 + lv32) + log_boost;
          ++c;
          need_init = true;
          pending = (c < numc);
        }
      }
    }
  }

  // ---- Phase 2: softmax + importance weights + moment accumulation ----
  float Greg[16];
#pragma unroll
  for (int k = 0; k < 16; ++k) Greg[k] = Gw[j * 16 + k];
  if (t == 0) { sM = -INFINITY; sS = 0.0f; sFac = 1.0f; }
  __syncthreads();   // slg_all complete + sM init

  float acc = 0.0f;     // zzy[k=h_sub][l=j]
  float zyacc = 0.0f;   // threads t<16 own zy[t]

  for (int cch = 0; cch < 32; ++cch) {
    int h = cch * 16 + h_sub;
    bool valid = (h < NSAMP);
    float lg = slg_all[cch][t];

    // row softmax via intra-wave shuffles (row = 16 contiguous lanes)
    float mx = lg;
    mx = fmaxf(mx, __shfl_xor(mx, 1, 16));
    mx = fmaxf(mx, __shfl_xor(mx, 2, 16));
    mx = fmaxf(mx, __shfl_xor(mx, 4, 16));
    mx = fmaxf(mx, __shfl_xor(mx, 8, 16));
    float ez = expf(lg - mx);
    float se = ez;
    se += __shfl_xor(se, 1, 16);
    se += __shfl_xor(se, 2, 16);
    se += __shfl_xor(se, 4, 16);
    se += __shfl_xor(se, 8, 16);
    float z = valid ? (ez / se) : 0.0f;
    sz[h_sub][j] = z;                      // same-wave readers below
    float lz = logf(z);
    float pq = admj * lz;                  // p2 - q contribution

    // quadratic form: (Gz)_j then z_j*((Gz)_j - 2u_j)
    float gz = 0.0f;
#pragma unroll
    for (int k = 0; k < 16; ++k) gz = fmaf(Greg[k], sz[h_sub][k], gz);
    float sres = z * (gz - uj2);

    pq   += __shfl_xor(pq, 1, 16);
    pq   += __shfl_xor(pq, 2, 16);
    pq   += __shfl_xor(pq, 4, 16);
    pq   += __shfl_xor(pq, 8, 16);
    sres += __shfl_xor(sres, 1, 16);
    sres += __shfl_xor(sres, 2, 16);
    sres += __shfl_xor(sres, 4, 16);
    sres += __shfl_xor(sres, 8, 16);

    if (j == 0) {
      float lw = -50.0f * sres + pq + cn;
      slw[h_sub] = valid ? lw : -INFINITY;
    }
    __syncthreads();   // B1: slw + all rows' sz visible

    if (t < 16) {
      float cmax = sM;
      for (int hh = 0; hh < 16; ++hh) cmax = fmaxf(cmax, slw[hh]);
      float w = expf(slw[t] - cmax);
      swv[t] = w;
      if (t == 0) {
        float f2 = expf(sM - cmax);
        float Snew = sS * f2;
        for (int hh = 0; hh < 16; ++hh) Snew += swv[hh];
        sM = cmax; sS = Snew; sFac = f2;
      }
    }
    __syncthreads();   // B2: swv, sFac visible

    float fc = sFac;
    acc *= fc;
#pragma unroll
    for (int hh = 0; hh < 16; ++hh)
      acc = fmaf(swv[hh] * sz[hh][h_sub], sz[hh][j], acc);
    if (t < 16) {
      zyacc *= fc;
#pragma unroll
      for (int hh = 0; hh < 16; ++hh) zyacc = fmaf(swv[hh], sz[hh][t], zyacc);
    }
    __syncthreads();   // B3: protect sz from next chunk's overwrite
  }

  float Sf = sS;
  if (t < 16) out[n * 16 + t] = zyacc / Sf;
  out[N_OBS * R_DIM + n * 256 + t] = acc / Sf;
}

extern "C" void kernel_launch(void* const* d_in, const int* in_sizes, int n_in,
                              void* d_out, int out_size, void* d_ws, size_t ws_size,
                              hipStream_t stream) {
  const float* y     = (const float*)d_in[0];
  const float* H     = (const float*)d_in[1];
  const float* alpha = (const float*)d_in[2];
  char* ws = (char*)d_ws;
  float* out = (float*)d_out;

  prep_kernel<<<1, 64, 0, stream>>>(H, alpha, ws);
  main_kernel<<<N_OBS, 256, 0, stream>>>(y, H, alpha, ws, out);
}

// Round 9
// 650.445 us; speedup vs baseline: 1.0107x; 1.0107x over previous
//
#include <hip/hip_runtime.h>
#include <cstdint>
#include <cmath>

#pragma clang fp contract(off)

#define N_OBS 2048
#define D_DIM 128
#define R_DIM 16
#define NSAMP 500

// ---- workspace layout (bytes) ----
#define WS_M     0        // 16 f32
#define WS_EY    64       // 128 f32
#define WS_GAIN  576      // 16*128 f32
#define WS_SCAL  8768     // scalars: [0]=trace_C, [1]=pconst, [2]=alpha0
#define WS_G     8800     // 16*16 f32  G = H^T H

// ---- f64-path f32 transcendentals: accept/reject-critical values only.
// Matching glibc/XLA-CPU rounding keeps the rejection stream aligned (round-2
// lesson). Acceptance test is margin-gated (round-7 win); erfinv's log1p stays
// f64 (round-8 lesson: gating it costs more than it saves).
__device__ __forceinline__ float flog(float x)   { return (float)log((double)x); }
__device__ __forceinline__ float flog1p(float x) { return (float)log1p((double)x); }

// ---------------- Threefry-2x32, 20 rounds (JAX-compatible) ----------------
__device__ __forceinline__ void tf_block(uint32_t k0, uint32_t k1,
                                         uint32_t x0, uint32_t x1,
                                         uint32_t& o0, uint32_t& o1) {
  const uint32_t k2 = k0 ^ k1 ^ 0x1BD11BDAu;
  x0 += k0; x1 += k1;
#define TF_R(r) { x0 += x1; x1 = (x1 << (r)) | (x1 >> (32 - (r))); x1 ^= x0; }
  TF_R(13) TF_R(15) TF_R(26) TF_R(6)
  x0 += k1; x1 += k2 + 1u;
  TF_R(17) TF_R(29) TF_R(16) TF_R(24)
  x0 += k2; x1 += k0 + 2u;
  TF_R(13) TF_R(15) TF_R(26) TF_R(6)
  x0 += k0; x1 += k1 + 3u;
  TF_R(17) TF_R(29) TF_R(16) TF_R(24)
  x0 += k1; x1 += k2 + 4u;
  TF_R(13) TF_R(15) TF_R(26) TF_R(6)
  x0 += k2; x1 += k0 + 5u;
#undef TF_R
  o0 = x0; o1 = x1;
}

__device__ __forceinline__ uint32_t rb32(uint32_t ka, uint32_t kb) {
  uint32_t o0, o1;
  tf_block(ka, kb, 0u, 0u, o0, o1);
  return o0 ^ o1;
}

__device__ __forceinline__ float u01(uint32_t bits) {
  uint32_t fb = (bits >> 9) | 0x3F800000u;
  return __uint_as_float(fb) - 1.0f;
}

// XLA f32 ErfInv polynomial (Giles); feeds the normal draw -> value must match
// the reference bitwise, so its log1p stays on the f64 path (not gateable).
__device__ __forceinline__ float erfinv_xla(float x) {
  float w = -flog1p(-(x * x));
  float p;
  if (w < 5.0f) {
    w = w - 2.5f;
    p = 2.81022636e-08f;
    p = 3.43273939e-07f + p * w;
    p = -3.5233877e-06f + p * w;
    p = -4.39150654e-06f + p * w;
    p = 0.00021858087f + p * w;
    p = -0.00125372503f + p * w;
    p = -0.00417768164f + p * w;
    p = 0.246640727f + p * w;
    p = 1.50140941f + p * w;
  } else {
    w = sqrtf(w) - 3.0f;
    p = -0.000200214257f;
    p = 0.000100950558f + p * w;
    p = 0.00134934322f + p * w;
    p = -0.00367342844f + p * w;
    p = 0.00573950773f + p * w;
    p = -0.0076224613f + p * w;
    p = 0.00943887047f + p * w;
    p = 1.00167406f + p * w;
    p = 2.83297682f + p * w;
  }
  return p * x;
}

__device__ __forceinline__ float normal_jax(uint32_t ka, uint32_t kb) {
  float f = u01(rb32(ka, kb));
  float u = f * 2.0f + (-0.99999994f);
  u = fmaxf(-0.99999994f, u);
  return 1.41421356f * erfinv_xla(u);
}

// ---------------- Kernel 1: LMMSE prep (1 wave, Woodbury 16x16) ----------------
__global__ __launch_bounds__(64) void prep_kernel(const float* __restrict__ H,
                                                  const float* __restrict__ alpha,
                                                  char* __restrict__ ws) {
  float* m    = (float*)(ws + WS_M);
  float* EY   = (float*)(ws + WS_EY);
  float* gain = (float*)(ws + WS_GAIN);
  float* scal = (float*)(ws + WS_SCAL);
  float* Gws  = (float*)(ws + WS_G);

  __shared__ float sH[128 * 16];
  __shared__ float sC[16][16];
  __shared__ float sHC[128 * 16];
  __shared__ float sm[16];
  __shared__ double sHtH[16][16];
  __shared__ double M[16][33];
  __shared__ double dfac[16];
  __shared__ double spiv;
  __shared__ int   spivrow;
  __shared__ float sgain[16 * 128];

  int t = threadIdx.x;
  for (int i = t; i < 2048; i += 64) sH[i] = H[i];
  __syncthreads();

  if (t == 0) {
    float a0 = 0.0f;
    for (int j = 0; j < 16; ++j) a0 += alpha[j];
    float pc = lgammaf(a0);
    for (int j = 0; j < 16; ++j) pc -= lgammaf(alpha[j]);
    scal[2] = a0; scal[1] = pc;
    for (int j = 0; j < 16; ++j) { sm[j] = alpha[j] / a0; m[j] = sm[j]; }
  }
  __syncthreads();
  float a0 = scal[2];

  for (int e = t; e < 256; e += 64) {
    int i = e >> 4, j = e & 15;
    float v = ((i == j) ? sm[i] : 0.0f) - sm[i] * sm[j];
    sC[i][j] = v / (a0 + 1.0f);
  }
  for (int dd = t; dd < 128; dd += 64) {
    float acc = 0.0f;
    for (int j = 0; j < 16; ++j) acc += sH[dd * 16 + j] * sm[j];
    EY[dd] = acc;
  }
  __syncthreads();

  for (int idx = t; idx < 2048; idx += 64) {
    int dd = idx >> 4, j = idx & 15;
    float acc = 0.0f;
    for (int i = 0; i < 16; ++i) acc += sH[dd * 16 + i] * sC[i][j];
    sHC[idx] = acc;
  }
  for (int e = t; e < 256; e += 64) {
    int i = e >> 4, j = e & 15;
    double acc = 0.0;
    for (int dd = 0; dd < 128; ++dd)
      acc += (double)sH[dd * 16 + i] * (double)sH[dd * 16 + j];
    sHtH[i][j] = acc;
    Gws[i * 16 + j] = (float)acc;
  }
  __syncthreads();

  for (int e = t; e < 256; e += 64) {
    int i = e >> 4, j = e & 15;
    double acc = (i == j) ? 0.01 : 0.0;
    for (int k = 0; k < 16; ++k) acc += (double)sC[i][k] * sHtH[k][j];
    M[i][j] = acc;
    M[i][16 + j] = (i == j) ? 1.0 : 0.0;
  }
  __syncthreads();

  for (int p = 0; p < 16; ++p) {
    if (t == 0) {
      int best = p; double bv = fabs(M[p][p]);
      for (int r = p + 1; r < 16; ++r) {
        double v = fabs(M[r][p]);
        if (v > bv) { bv = v; best = r; }
      }
      spivrow = best;
    }
    __syncthreads();
    int pr = spivrow;
    double va = 0.0, vb = 0.0;
    if (t < 32 && pr != p) { va = M[p][t]; vb = M[pr][t]; }
    __syncthreads();
    if (t < 32 && pr != p) { M[p][t] = vb; M[pr][t] = va; }
    __syncthreads();
    if (t == 0) spiv = 1.0 / M[p][p];
    __syncthreads();
    if (t < 32) M[p][t] *= spiv;
    if (t < 16) dfac[t] = M[t][p];
    __syncthreads();
    for (int e = t; e < 512; e += 64) {
      int r = e >> 5, c = e & 31;
      if (r != p) M[r][c] -= dfac[r] * M[p][c];
    }
    __syncthreads();
  }

  for (int idx = t; idx < 2048; idx += 64) {
    int j = idx >> 7, dd = idx & 127;
    double acc = 0.0;
    for (int k = 0; k < 16; ++k) acc += M[j][16 + k] * (double)sHC[dd * 16 + k];
    float g = (float)acc;
    sgain[j * 128 + dd] = g;
    gain[j * 128 + dd] = g;
  }
  __syncthreads();

  if (t == 0) {
    float tr = 0.0f;
    for (int j = 0; j < 16; ++j) {
      float s2 = 0.0f;
      for (int dd = 0; dd < 128; ++dd) s2 += sgain[j * 128 + dd] * sHC[dd * 16 + j];
      tr += sC[j][j] - s2;
    }
    tr = fmaxf(tr, 0.0f) + 1e-6f;
    scal[0] = tr;
  }
}

// ---------------- Kernel 2: fused per-n prep + sampling + moments ----------------
__global__ __launch_bounds__(256) void main_kernel(const float* __restrict__ y,
                                                   const float* __restrict__ Hg,
                                                   const float* __restrict__ alpha,
                                                   const char* __restrict__ ws,
                                                   float* __restrict__ out) {
  const float* mws  = (const float*)(ws + WS_M);
  const float* EYw  = (const float*)(ws + WS_EY);
  const float* gain = (const float*)(ws + WS_GAIN);
  const float* scal = (const float*)(ws + WS_SCAL);
  const float* Gw   = (const float*)(ws + WS_G);

  __shared__ float slg_all[32][256];   // lg for all chunks (32 KB); prologue aliases it
  __shared__ float sz[16][17];
  __shared__ float slw[16], swv[16];
  __shared__ float sdiri[16], su2[16], stv[16];
  __shared__ float smisc[2];           // [0]=cn
  __shared__ float sM, sS, sFac;

  int t = threadIdx.x;
  int n = blockIdx.x;
  int h_sub = t >> 4, j = t & 15;

  // ---- Phase 0: per-n proposal concentrations (bitwise replay of diri_kernel) ----
  {
    float* sGainT = &slg_all[0][0];      // [128][17]: gain transposed, padded
    float* sHs    = sGainT + 2176;       // [128][16]
    float* sys    = sHs + 2048;          // [128]
    float* sEYs   = sys + 128;           // [128]
    for (int i = t; i < 2048; i += 256) {
      sGainT[(i & 127) * 17 + (i >> 7)] = gain[i];   // stride-17: conflict-free
      sHs[i] = Hg[i];
    }
    if (t < 128) { sys[t] = y[n * 128 + t]; sEYs[t] = EYw[t]; }
    __syncthreads();
    if (t < 16) {
      float tv = mws[t];
      float u = 0.0f;
      for (int dd = 0; dd < 128; ++dd) {
        float yv = sys[dd];
        float dy = yv - sEYs[dd];
        tv += dy * sGainT[dd * 17 + t];
        u  += yv * sHs[dd * 16 + t];
      }
      stv[t] = tv;
      su2[t] = 2.0f * u;
    }
    __syncthreads();
    if (t == 0) {
      float yy = 0.0f;
      for (int dd = 0; dd < 128; ++dd) yy += sys[dd] * sys[dd];
      float s = 0.0f;
      for (int jj = 0; jj < 16; ++jj) {
        float v = fmaxf(stv[jj], 0.0f) + 1e-6f; stv[jj] = v; s += v;
      }
      float ssq = 0.0f;
      for (int jj = 0; jj < 16; ++jj) {
        float v = stv[jj] / s; stv[jj] = v; ssq += v * v;
      }
      float k = (1.0f - ssq) / scal[0] - 1.0f;
      float dsum = 0.0f, lgs = 0.0f;
      for (int jj = 0; jj < 16; ++jj) {
        float dj = fmaxf(k * stv[jj], 0.0f) + 0.8f;
        sdiri[jj] = dj; dsum += dj; lgs += lgammaf(dj);
      }
      float qcn = lgammaf(dsum) - lgs;
      smisc[0] = scal[1] - qcn - 50.0f * yy;   // lw = -50*(zGz-2zu) + (p2-q) + cn
    }
    __syncthreads();
  }

  float aj   = sdiri[j];
  float uj2  = su2[j];
  float cn   = smisc[0];
  float admj = alpha[j] - aj;

  // ---- Phase 1: self-paced sampling (round-7 sampler, byte-for-byte) ----
  {
    bool boost = (aj >= 1.0f);
    float aa = boost ? aj : (aj + 1.0f);
    float d  = aa - 0.33333334f;
    float cc = 0.33333334f / sqrtf(d);
    float inv_a = 1.0f / aj;
    float ld32 = logf(d);                    // loop-invariant (accept-path value)
    int numc = (h_sub < 4) ? 32 : 31;        // h = 16c+h_sub < 500
    int c = 0;
    bool need_init = true;
    bool pending = true;
    uint32_t kcx = 0, kcy = 0;
    float log_samples = 0.0f;

    while (__ballot(pending)) {
      if (pending) {
        if (need_init) {
          int h = c * 16 + h_sub;
          uint32_t jf = (((uint32_t)h * 2048u + (uint32_t)n) << 4) | (uint32_t)j;
          uint32_t ka, kb, ska, skb;
          tf_block(0u, 42u, 0u, jf, ka, kb);     // per-sample key (foldlike split)
          tf_block(ka, kb, 0u, 0u, kcx, kcy);    // carried key
          tf_block(ka, kb, 0u, 1u, ska, skb);    // subkey -> exponential
          float ef = u01(rb32(ska, skb));
          log_samples = log1pf(-ef);             // continuous -> f32
          need_init = false;
        }
        // one Marsaglia-Tsang outer iteration
        uint32_t xka, xkb, Uka, Ukb;
        tf_block(kcx, kcy, 0u, 1u, xka, xkb);    // x_key
        tf_block(kcx, kcy, 0u, 2u, Uka, Ukb);    // U_key
        float x = 0.0f, v = -1.0f;
        for (int in = 0; in < 256; ++in) {
          uint32_t sxa, sxb;
          tf_block(xka, xkb, 0u, 1u, sxa, sxb);  // subkey for normal
          x = normal_jax(sxa, sxb);
          v = 1.0f + x * cc;
          if (v > 0.0f) break;
          uint32_t nxa, nxb;
          tf_block(xka, xkb, 0u, 0u, nxa, nxb);  // lazy inner carry
          xka = nxa; xkb = nxb;
        }
        float X = x * x;
        float V = (v * v) * v;
        float U = u01(rb32(Uka, Ukb));
        float lv32 = logf(V);                    // test fast-path + accept output
        // continue while BOTH hold; accept when either fails.
        bool cont = (U >= 1.0f - 0.0331f * (X * X));
        if (cont) {
          // margin-gated log test: f32 fast path, f64 fallback at the boundary.
          float lu32  = logf(U);
          float rhs32 = X * 0.5f + d * ((1.0f - V) + lv32);
          float margin = lu32 - rhs32;
          float thr = 4.8e-7f * fabsf(lu32)
                    + 4.8e-7f * d * fabsf(lv32)
                    + 1.2e-7f * (fabsf(rhs32) + X)
                    + 1e-7f;
          if (fabsf(margin) > thr) {
            cont = (margin >= 0.0f);
          } else {
            cont = (flog(U) >= X * 0.5f + d * ((1.0f - V) + flog(V)));
          }
        }
        if (cont) {
          uint32_t kna, knb;
          tf_block(kcx, kcy, 0u, 0u, kna, knb);  // lazy outer carry
          kcx = kna; kcy = knb;
        } else {
          float log_boost = (boost || log_samples == 0.0f)
                              ? 0.0f : log_samples * inv_a;
          slg_all[c][t] = (ld32 + lv32) + log_boost;  // == (logf(d)+logf(V))+boost
          ++c;
          need_init = true;
          pending = (c < numc);
        }
      }
    }
  }

  // ---- Phase 2: softmax + importance weights + moment accumulation ----
  float Greg[16];
#pragma unroll
  for (int k = 0; k < 16; ++k) Greg[k] = Gw[j * 16 + k];
  if (t == 0) { sM = -INFINITY; sS = 0.0f; sFac = 1.0f; }
  __syncthreads();   // slg_all complete + sM init

  float acc = 0.0f;     // zzy[k=h_sub][l=j]
  float zyacc = 0.0f;   // threads t<16 own zy[t]

  for (int cch = 0; cch < 32; ++cch) {
    int h = cch * 16 + h_sub;
    bool valid = (h < NSAMP);
    float lg = slg_all[cch][t];

    // row softmax via intra-wave shuffles (row = 16 contiguous lanes)
    float mx = lg;
    mx = fmaxf(mx, __shfl_xor(mx, 1, 16));
    mx = fmaxf(mx, __shfl_xor(mx, 2, 16));
    mx = fmaxf(mx, __shfl_xor(mx, 4, 16));
    mx = fmaxf(mx, __shfl_xor(mx, 8, 16));
    float ez = expf(lg - mx);
    float se = ez;
    se += __shfl_xor(se, 1, 16);
    se += __shfl_xor(se, 2, 16);
    se += __shfl_xor(se, 4, 16);
    se += __shfl_xor(se, 8, 16);
    float z = valid ? (ez / se) : 0.0f;
    sz[h_sub][j] = z;                      // same-wave readers below
    float lz = logf(z);
    float pq = admj * lz;                  // p2 - q contribution

    // quadratic form: (Gz)_j then z_j*((Gz)_j - 2u_j)
    float gz = 0.0f;
#pragma unroll
    for (int k = 0; k < 16; ++k) gz = fmaf(Greg[k], sz[h_sub][k], gz);
    float sres = z * (gz - uj2);

    pq   += __shfl_xor(pq, 1, 16);
    pq   += __shfl_xor(pq, 2, 16);
    pq   += __shfl_xor(pq, 4, 16);
    pq   += __shfl_xor(pq, 8, 16);
    sres += __shfl_xor(sres, 1, 16);
    sres += __shfl_xor(sres, 2, 16);
    sres += __shfl_xor(sres, 4, 16);
    sres += __shfl_xor(sres, 8, 16);

    if (j == 0) {
      float lw = -50.0f * sres + pq + cn;
      slw[h_sub] = valid ? lw : -INFINITY;
    }
    __syncthreads();   // B1: slw + all rows' sz visible

    if (t < 16) {
      float cmax = sM;
      for (int hh = 0; hh < 16; ++hh) cmax = fmaxf(cmax, slw[hh]);
      float w = expf(slw[t] - cmax);
      swv[t] = w;
      if (t == 0) {
        float f2 = expf(sM - cmax);
        float Snew = sS * f2;
        for (int hh = 0; hh < 16; ++hh) Snew += swv[hh];
        sM = cmax; sS = Snew; sFac = f2;
      }
    }
    __syncthreads();   // B2: swv, sFac visible

    float fc = sFac;
    acc *= fc;
#pragma unroll
    for (int hh = 0; hh < 16; ++hh)
      acc = fmaf(swv[hh] * sz[hh][h_sub], sz[hh][j], acc);
    if (t < 16) {
      zyacc *= fc;
#pragma unroll
      for (int hh = 0; hh < 16; ++hh) zyacc = fmaf(swv[hh], sz[hh][t], zyacc);
    }
    __syncthreads();   // B3: protect sz from next chunk's overwrite
  }

  float Sf = sS;
  if (t < 16) out[n * 16 + t] = zyacc / Sf;
  out[N_OBS * R_DIM + n * 256 + t] = acc / Sf;
}

extern "C" void kernel_launch(void* const* d_in, const int* in_sizes, int n_in,
                              void* d_out, int out_size, void* d_ws, size_t ws_size,
                              hipStream_t stream) {
  const float* y     = (const float*)d_in[0];
  const float* H     = (const float*)d_in[1];
  const float* alpha = (const float*)d_in[2];
  char* ws = (char*)d_ws;
  float* out = (float*)d_out;

  prep_kernel<<<1, 64, 0, stream>>>(H, alpha, ws);
  main_kernel<<<N_OBS, 256, 0, stream>>>(y, H, alpha, ws, out);
}

// Round 10
// 615.201 us; speedup vs baseline: 1.0686x; 1.0573x over previous
//
#include <hip/hip_runtime.h>
#include <cstdint>
#include <cmath>

#pragma clang fp contract(off)

#define N_OBS 2048
#define D_DIM 128
#define R_DIM 16
#define NSAMP 500

// ---- workspace layout (bytes) ----
#define WS_M     0        // 16 f32
#define WS_EY    64       // 128 f32
#define WS_GAIN  576      // 16*128 f32
#define WS_SCAL  8768     // scalars: [0]=trace_C, [1]=pconst, [2]=alpha0
#define WS_G     8800     // 16*16 f32  G = H^T H

// ---- f64-path f32 transcendentals: accept/reject-critical values only.
// Matching glibc/XLA-CPU rounding keeps the rejection stream aligned (round-2
// lesson). Acceptance test is margin-gated (round-7 win); erfinv's log1p stays
// f64 (round-8 lesson: gating it costs more than it saves).
__device__ __forceinline__ float flog(float x)   { return (float)log((double)x); }
__device__ __forceinline__ float flog1p(float x) { return (float)log1p((double)x); }

// ---------------- Threefry-2x32, 20 rounds (JAX-compatible) ----------------
__device__ __forceinline__ void tf_block(uint32_t k0, uint32_t k1,
                                         uint32_t x0, uint32_t x1,
                                         uint32_t& o0, uint32_t& o1) {
  const uint32_t k2 = k0 ^ k1 ^ 0x1BD11BDAu;
  x0 += k0; x1 += k1;
#define TF_R(r) { x0 += x1; x1 = (x1 << (r)) | (x1 >> (32 - (r))); x1 ^= x0; }
  TF_R(13) TF_R(15) TF_R(26) TF_R(6)
  x0 += k1; x1 += k2 + 1u;
  TF_R(17) TF_R(29) TF_R(16) TF_R(24)
  x0 += k2; x1 += k0 + 2u;
  TF_R(13) TF_R(15) TF_R(26) TF_R(6)
  x0 += k0; x1 += k1 + 3u;
  TF_R(17) TF_R(29) TF_R(16) TF_R(24)
  x0 += k1; x1 += k2 + 4u;
  TF_R(13) TF_R(15) TF_R(26) TF_R(6)
  x0 += k2; x1 += k0 + 5u;
#undef TF_R
  o0 = x0; o1 = x1;
}

__device__ __forceinline__ uint32_t rb32(uint32_t ka, uint32_t kb) {
  uint32_t o0, o1;
  tf_block(ka, kb, 0u, 0u, o0, o1);
  return o0 ^ o1;
}

__device__ __forceinline__ float u01(uint32_t bits) {
  uint32_t fb = (bits >> 9) | 0x3F800000u;
  return __uint_as_float(fb) - 1.0f;
}

// XLA f32 ErfInv polynomial (Giles); feeds the normal draw -> value must match
// the reference bitwise, so its log1p stays on the f64 path (not gateable).
__device__ __forceinline__ float erfinv_xla(float x) {
  float w = -flog1p(-(x * x));
  float p;
  if (w < 5.0f) {
    w = w - 2.5f;
    p = 2.81022636e-08f;
    p = 3.43273939e-07f + p * w;
    p = -3.5233877e-06f + p * w;
    p = -4.39150654e-06f + p * w;
    p = 0.00021858087f + p * w;
    p = -0.00125372503f + p * w;
    p = -0.00417768164f + p * w;
    p = 0.246640727f + p * w;
    p = 1.50140941f + p * w;
  } else {
    w = sqrtf(w) - 3.0f;
    p = -0.000200214257f;
    p = 0.000100950558f + p * w;
    p = 0.00134934322f + p * w;
    p = -0.00367342844f + p * w;
    p = 0.00573950773f + p * w;
    p = -0.0076224613f + p * w;
    p = 0.00943887047f + p * w;
    p = 1.00167406f + p * w;
    p = 2.83297682f + p * w;
  }
  return p * x;
}

__device__ __forceinline__ float normal_jax(uint32_t ka, uint32_t kb) {
  float f = u01(rb32(ka, kb));
  float u = f * 2.0f + (-0.99999994f);
  u = fmaxf(-0.99999994f, u);
  return 1.41421356f * erfinv_xla(u);
}

// ---------------- Kernel 1: LMMSE prep (1 wave, Woodbury 16x16) ----------------
__global__ __launch_bounds__(64) void prep_kernel(const float* __restrict__ H,
                                                  const float* __restrict__ alpha,
                                                  char* __restrict__ ws) {
  float* m    = (float*)(ws + WS_M);
  float* EY   = (float*)(ws + WS_EY);
  float* gain = (float*)(ws + WS_GAIN);
  float* scal = (float*)(ws + WS_SCAL);
  float* Gws  = (float*)(ws + WS_G);

  __shared__ float sH[128 * 16];
  __shared__ float sC[16][16];
  __shared__ float sHC[128 * 16];
  __shared__ float sm[16];
  __shared__ double sHtH[16][16];
  __shared__ double M[16][33];
  __shared__ double dfac[16];
  __shared__ double spiv;
  __shared__ int   spivrow;
  __shared__ float sgain[16 * 128];

  int t = threadIdx.x;
  for (int i = t; i < 2048; i += 64) sH[i] = H[i];
  __syncthreads();

  if (t == 0) {
    float a0 = 0.0f;
    for (int j = 0; j < 16; ++j) a0 += alpha[j];
    scal[2] = a0;
    for (int j = 0; j < 16; ++j) { sm[j] = alpha[j] / a0; m[j] = sm[j]; }
  }
  __syncthreads();
  float a0 = scal[2];

  for (int e = t; e < 256; e += 64) {
    int i = e >> 4, j = e & 15;
    float v = ((i == j) ? sm[i] : 0.0f) - sm[i] * sm[j];
    sC[i][j] = v / (a0 + 1.0f);
  }
  for (int dd = t; dd < 128; dd += 64) {
    float acc = 0.0f;
    for (int j = 0; j < 16; ++j) acc += sH[dd * 16 + j] * sm[j];
    EY[dd] = acc;
  }
  __syncthreads();

  for (int idx = t; idx < 2048; idx += 64) {
    int dd = idx >> 4, j = idx & 15;
    float acc = 0.0f;
    for (int i = 0; i < 16; ++i) acc += sH[dd * 16 + i] * sC[i][j];
    sHC[idx] = acc;
  }
  for (int e = t; e < 256; e += 64) {
    int i = e >> 4, j = e & 15;
    double acc = 0.0;
    for (int dd = 0; dd < 128; ++dd)
      acc += (double)sH[dd * 16 + i] * (double)sH[dd * 16 + j];
    sHtH[i][j] = acc;
    Gws[i * 16 + j] = (float)acc;
  }
  __syncthreads();

  for (int e = t; e < 256; e += 64) {
    int i = e >> 4, j = e & 15;
    double acc = (i == j) ? 0.01 : 0.0;
    for (int k = 0; k < 16; ++k) acc += (double)sC[i][k] * sHtH[k][j];
    M[i][j] = acc;
    M[i][16 + j] = (i == j) ? 1.0 : 0.0;
  }
  __syncthreads();

  for (int p = 0; p < 16; ++p) {
    if (t == 0) {
      int best = p; double bv = fabs(M[p][p]);
      for (int r = p + 1; r < 16; ++r) {
        double v = fabs(M[r][p]);
        if (v > bv) { bv = v; best = r; }
      }
      spivrow = best;
    }
    __syncthreads();
    int pr = spivrow;
    double va = 0.0, vb = 0.0;
    if (t < 32 && pr != p) { va = M[p][t]; vb = M[pr][t]; }
    __syncthreads();
    if (t < 32 && pr != p) { M[p][t] = vb; M[pr][t] = va; }
    __syncthreads();
    if (t == 0) spiv = 1.0 / M[p][p];
    __syncthreads();
    if (t < 32) M[p][t] *= spiv;
    if (t < 16) dfac[t] = M[t][p];
    __syncthreads();
    for (int e = t; e < 512; e += 64) {
      int r = e >> 5, c = e & 31;
      if (r != p) M[r][c] -= dfac[r] * M[p][c];
    }
    __syncthreads();
  }

  for (int idx = t; idx < 2048; idx += 64) {
    int j = idx >> 7, dd = idx & 127;
    double acc = 0.0;
    for (int k = 0; k < 16; ++k) acc += M[j][16 + k] * (double)sHC[dd * 16 + k];
    float g = (float)acc;
    sgain[j * 128 + dd] = g;
    gain[j * 128 + dd] = g;
  }
  __syncthreads();

  if (t == 0) {
    float tr = 0.0f;
    for (int j = 0; j < 16; ++j) {
      float s2 = 0.0f;
      for (int dd = 0; dd < 128; ++dd) s2 += sgain[j * 128 + dd] * sHC[dd * 16 + j];
      tr += sC[j][j] - s2;
    }
    tr = fmaxf(tr, 0.0f) + 1e-6f;
    scal[0] = tr;
  }
}

// ---------------- Kernel 2: fused per-n prep + sampling + moments ----------------
// Phase 0 computes only diri + u (no lgamma/yy: the per-n constant cn is
// dropped from lw — softmax is shift-invariant, so weights are unchanged up
// to last-ulp rounding). Keeping lgammaf out of this kernel keeps VGPR low
// (round-9 lesson: inlined lgammaf drove VGPR 52->80, -50us).
__global__ __launch_bounds__(256) void main_kernel(const float* __restrict__ y,
                                                   const float* __restrict__ Hg,
                                                   const float* __restrict__ alpha,
                                                   const char* __restrict__ ws,
                                                   float* __restrict__ out) {
  const float* mws  = (const float*)(ws + WS_M);
  const float* EYw  = (const float*)(ws + WS_EY);
  const float* gain = (const float*)(ws + WS_GAIN);
  const float* scal = (const float*)(ws + WS_SCAL);
  const float* Gw   = (const float*)(ws + WS_G);

  __shared__ float slg_all[32][256];   // lg for all chunks (32 KB); prologue aliases it
  __shared__ float sz[16][17];
  __shared__ float slw[16], swv[16];
  __shared__ float sdiri[16], su2[16], stv[16];
  __shared__ float sM, sS, sFac;

  int t = threadIdx.x;
  int n = blockIdx.x;
  int h_sub = t >> 4, j = t & 15;

  // ---- Phase 0: per-n proposal concentrations (tv/u dots; NO lgamma) ----
  {
    float* sGainT = &slg_all[0][0];      // [128][17]: gain transposed, padded
    float* sHs    = sGainT + 2176;       // [128][16]
    float* sys    = sHs + 2048;          // [128]
    float* sEYs   = sys + 128;           // [128]
    for (int i = t; i < 2048; i += 256) {
      sGainT[(i & 127) * 17 + (i >> 7)] = gain[i];   // stride-17: conflict-free
      sHs[i] = Hg[i];
    }
    if (t < 128) { sys[t] = y[n * 128 + t]; sEYs[t] = EYw[t]; }
    __syncthreads();
    if (t < 16) {
      float tv = mws[t];
      float u = 0.0f;
      for (int dd = 0; dd < 128; ++dd) {
        float yv = sys[dd];
        float dy = yv - sEYs[dd];
        tv += dy * sGainT[dd * 17 + t];
        u  += yv * sHs[dd * 16 + t];
      }
      stv[t] = tv;
      su2[t] = 2.0f * u;
    }
    __syncthreads();
    if (t == 0) {
      float s = 0.0f;
      for (int jj = 0; jj < 16; ++jj) {
        float v = fmaxf(stv[jj], 0.0f) + 1e-6f; stv[jj] = v; s += v;
      }
      float ssq = 0.0f;
      for (int jj = 0; jj < 16; ++jj) {
        float v = stv[jj] / s; stv[jj] = v; ssq += v * v;
      }
      float k = (1.0f - ssq) / scal[0] - 1.0f;
      for (int jj = 0; jj < 16; ++jj)
        sdiri[jj] = fmaxf(k * stv[jj], 0.0f) + 0.8f;
      sM = -INFINITY; sS = 0.0f; sFac = 1.0f;
    }
    __syncthreads();
  }

  float aj   = sdiri[j];
  float uj2  = su2[j];
  float admj = alpha[j] - aj;

  // ---- Phase 1: self-paced sampling (round-7 sampler, byte-for-byte) ----
  {
    bool boost = (aj >= 1.0f);
    float aa = boost ? aj : (aj + 1.0f);
    float d  = aa - 0.33333334f;
    float cc = 0.33333334f / sqrtf(d);
    float inv_a = 1.0f / aj;
    float ld32 = logf(d);                    // loop-invariant (accept-path value)
    int numc = (h_sub < 4) ? 32 : 31;        // h = 16c+h_sub < 500
    int c = 0;
    bool need_init = true;
    bool pending = true;
    uint32_t kcx = 0, kcy = 0;
    float log_samples = 0.0f;

    while (__ballot(pending)) {
      if (pending) {
        if (need_init) {
          int h = c * 16 + h_sub;
          uint32_t jf = (((uint32_t)h * 2048u + (uint32_t)n) << 4) | (uint32_t)j;
          uint32_t ka, kb, ska, skb;
          tf_block(0u, 42u, 0u, jf, ka, kb);     // per-sample key (foldlike split)
          tf_block(ka, kb, 0u, 0u, kcx, kcy);    // carried key
          tf_block(ka, kb, 0u, 1u, ska, skb);    // subkey -> exponential
          float ef = u01(rb32(ska, skb));
          log_samples = log1pf(-ef);             // continuous -> f32
          need_init = false;
        }
        // one Marsaglia-Tsang outer iteration
        uint32_t xka, xkb, Uka, Ukb;
        tf_block(kcx, kcy, 0u, 1u, xka, xkb);    // x_key
        tf_block(kcx, kcy, 0u, 2u, Uka, Ukb);    // U_key
        float x = 0.0f, v = -1.0f;
        for (int in = 0; in < 256; ++in) {
          uint32_t sxa, sxb;
          tf_block(xka, xkb, 0u, 1u, sxa, sxb);  // subkey for normal
          x = normal_jax(sxa, sxb);
          v = 1.0f + x * cc;
          if (v > 0.0f) break;
          uint32_t nxa, nxb;
          tf_block(xka, xkb, 0u, 0u, nxa, nxb);  // lazy inner carry
          xka = nxa; xkb = nxb;
        }
        float X = x * x;
        float V = (v * v) * v;
        float U = u01(rb32(Uka, Ukb));
        float lv32 = logf(V);                    // test fast-path + accept output
        // continue while BOTH hold; accept when either fails.
        bool cont = (U >= 1.0f - 0.0331f * (X * X));
        if (cont) {
          // margin-gated log test: f32 fast path, f64 fallback at the boundary.
          float lu32  = logf(U);
          float rhs32 = X * 0.5f + d * ((1.0f - V) + lv32);
          float margin = lu32 - rhs32;
          float thr = 4.8e-7f * fabsf(lu32)
                    + 4.8e-7f * d * fabsf(lv32)
                    + 1.2e-7f * (fabsf(rhs32) + X)
                    + 1e-7f;
          if (fabsf(margin) > thr) {
            cont = (margin >= 0.0f);
          } else {
            cont = (flog(U) >= X * 0.5f + d * ((1.0f - V) + flog(V)));
          }
        }
        if (cont) {
          uint32_t kna, knb;
          tf_block(kcx, kcy, 0u, 0u, kna, knb);  // lazy outer carry
          kcx = kna; kcy = knb;
        } else {
          float log_boost = (boost || log_samples == 0.0f)
                              ? 0.0f : log_samples * inv_a;
          slg_all[c][t] = (ld32 + lv32) + log_boost;  // == (logf(d)+logf(V))+boost
          ++c;
          need_init = true;
          pending = (c < numc);
        }
      }
    }
  }

  // ---- Phase 2: softmax + importance weights + moment accumulation ----
  float Greg[16];
#pragma unroll
  for (int k = 0; k < 16; ++k) Greg[k] = Gw[j * 16 + k];
  __syncthreads();   // slg_all complete (sM init done in Phase 0)

  float acc = 0.0f;     // zzy[k=h_sub][l=j]
  float zyacc = 0.0f;   // threads t<16 own zy[t]

  for (int cch = 0; cch < 32; ++cch) {
    int h = cch * 16 + h_sub;
    bool valid = (h < NSAMP);
    float lg = slg_all[cch][t];

    // row softmax via intra-wave shuffles (row = 16 contiguous lanes)
    float mx = lg;
    mx = fmaxf(mx, __shfl_xor(mx, 1, 16));
    mx = fmaxf(mx, __shfl_xor(mx, 2, 16));
    mx = fmaxf(mx, __shfl_xor(mx, 4, 16));
    mx = fmaxf(mx, __shfl_xor(mx, 8, 16));
    float ez = expf(lg - mx);
    float se = ez;
    se += __shfl_xor(se, 1, 16);
    se += __shfl_xor(se, 2, 16);
    se += __shfl_xor(se, 4, 16);
    se += __shfl_xor(se, 8, 16);
    float z = valid ? (ez / se) : 0.0f;
    sz[h_sub][j] = z;                      // same-wave readers below
    float lz = logf(z);
    float pq = admj * lz;                  // p2 - q contribution

    // quadratic form: (Gz)_j then z_j*((Gz)_j - 2u_j)
    float gz = 0.0f;
#pragma unroll
    for (int k = 0; k < 16; ++k) gz = fmaf(Greg[k], sz[h_sub][k], gz);
    float sres = z * (gz - uj2);

    pq   += __shfl_xor(pq, 1, 16);
    pq   += __shfl_xor(pq, 2, 16);
    pq   += __shfl_xor(pq, 4, 16);
    pq   += __shfl_xor(pq, 8, 16);
    sres += __shfl_xor(sres, 1, 16);
    sres += __shfl_xor(sres, 2, 16);
    sres += __shfl_xor(sres, 4, 16);
    sres += __shfl_xor(sres, 8, 16);

    if (j == 0) {
      // cn (per-n constant: pconst - qc_n - 50*||y||^2) dropped:
      // softmax over h is shift-invariant.
      float lw = -50.0f * sres + pq;
      slw[h_sub] = valid ? lw : -INFINITY;
    }
    __syncthreads();   // B1: slw + all rows' sz visible

    if (t < 16) {
      float cmax = sM;
      for (int hh = 0; hh < 16; ++hh) cmax = fmaxf(cmax, slw[hh]);
      float w = expf(slw[t] - cmax);
      swv[t] = w;
      if (t == 0) {
        float f2 = expf(sM - cmax);
        float Snew = sS * f2;
        for (int hh = 0; hh < 16; ++hh) Snew += swv[hh];
        sM = cmax; sS = Snew; sFac = f2;
      }
    }
    __syncthreads();   // B2: swv, sFac visible

    float fc = sFac;
    acc *= fc;
#pragma unroll
    for (int hh = 0; hh < 16; ++hh)
      acc = fmaf(swv[hh] * sz[hh][h_sub], sz[hh][j], acc);
    if (t < 16) {
      zyacc *= fc;
#pragma unroll
      for (int hh = 0; hh < 16; ++hh) zyacc = fmaf(swv[hh], sz[hh][t], zyacc);
    }
    __syncthreads();   // B3: protect sz from next chunk's overwrite
  }

  float Sf = sS;
  if (t < 16) out[n * 16 + t] = zyacc / Sf;
  out[N_OBS * R_DIM + n * 256 + t] = acc / Sf;
}

extern "C" void kernel_launch(void* const* d_in, const int* in_sizes, int n_in,
                              void* d_out, int out_size, void* d_ws, size_t ws_size,
                              hipStream_t stream) {
  const float* y     = (const float*)d_in[0];
  const float* H     = (const float*)d_in[1];
  const float* alpha = (const float*)d_in[2];
  char* ws = (char*)d_ws;
  float* out = (float*)d_out;

  prep_kernel<<<1, 64, 0, stream>>>(H, alpha, ws);
  main_kernel<<<N_OBS, 256, 0, stream>>>(y, H, alpha, ws, out);
}

// Round 11
// 591.083 us; speedup vs baseline: 1.1122x; 1.0408x over previous
//
#include <hip/hip_runtime.h>
#include <cstdint>
#include <cmath>

#pragma clang fp contract(off)

#define N_OBS 2048
#define D_DIM 128
#define R_DIM 16
#define NSAMP 500

// ---- workspace layout (bytes) ----
#define WS_M     0        // 16 f32
#define WS_EY    64       // 128 f32
#define WS_GAIN  576      // 16*128 f32
#define WS_SCAL  8768     // scalars: [0]=trace_C, [1]=pconst, [2]=alpha0
#define WS_G     8800     // 16*16 f32  G = H^T H

// ---- f64-path f32 transcendentals: used ONLY in the rare margin-gate
// fallback of the acceptance test (round-7 structure). Round-11: erfinv's
// log1p moved to plain f32 (expected ~1 accept/reject flip device-wide;
// bounded ~1e-3 output perturbation at isolated n — see journal).
__device__ __forceinline__ float flog(float x)   { return (float)log((double)x); }
__device__ __forceinline__ float flog1p(float x) { return (float)log1p((double)x); }

// ---------------- Threefry-2x32, 20 rounds (JAX-compatible) ----------------
__device__ __forceinline__ void tf_block(uint32_t k0, uint32_t k1,
                                         uint32_t x0, uint32_t x1,
                                         uint32_t& o0, uint32_t& o1) {
  const uint32_t k2 = k0 ^ k1 ^ 0x1BD11BDAu;
  x0 += k0; x1 += k1;
#define TF_R(r) { x0 += x1; x1 = (x1 << (r)) | (x1 >> (32 - (r))); x1 ^= x0; }
  TF_R(13) TF_R(15) TF_R(26) TF_R(6)
  x0 += k1; x1 += k2 + 1u;
  TF_R(17) TF_R(29) TF_R(16) TF_R(24)
  x0 += k2; x1 += k0 + 2u;
  TF_R(13) TF_R(15) TF_R(26) TF_R(6)
  x0 += k0; x1 += k1 + 3u;
  TF_R(17) TF_R(29) TF_R(16) TF_R(24)
  x0 += k1; x1 += k2 + 4u;
  TF_R(13) TF_R(15) TF_R(26) TF_R(6)
  x0 += k2; x1 += k0 + 5u;
#undef TF_R
  o0 = x0; o1 = x1;
}

__device__ __forceinline__ uint32_t rb32(uint32_t ka, uint32_t kb) {
  uint32_t o0, o1;
  tf_block(ka, kb, 0u, 0u, o0, o1);
  return o0 ^ o1;
}

__device__ __forceinline__ float u01(uint32_t bits) {
  uint32_t fb = (bits >> 9) | 0x3F800000u;
  return __uint_as_float(fb) - 1.0f;
}

// XLA f32 ErfInv polynomial (Giles). Round-11: f32 log1pf (ungated — the
// downstream accept test is itself margin-gated, so only ~1e-8/draw flip risk).
__device__ __forceinline__ float erfinv_xla(float x) {
  float w = -log1pf(-(x * x));
  float p;
  if (w < 5.0f) {
    w = w - 2.5f;
    p = 2.81022636e-08f;
    p = 3.43273939e-07f + p * w;
    p = -3.5233877e-06f + p * w;
    p = -4.39150654e-06f + p * w;
    p = 0.00021858087f + p * w;
    p = -0.00125372503f + p * w;
    p = -0.00417768164f + p * w;
    p = 0.246640727f + p * w;
    p = 1.50140941f + p * w;
  } else {
    w = sqrtf(w) - 3.0f;
    p = -0.000200214257f;
    p = 0.000100950558f + p * w;
    p = 0.00134934322f + p * w;
    p = -0.00367342844f + p * w;
    p = 0.00573950773f + p * w;
    p = -0.0076224613f + p * w;
    p = 0.00943887047f + p * w;
    p = 1.00167406f + p * w;
    p = 2.83297682f + p * w;
  }
  return p * x;
}

__device__ __forceinline__ float normal_jax(uint32_t ka, uint32_t kb) {
  float f = u01(rb32(ka, kb));
  float u = f * 2.0f + (-0.99999994f);
  u = fmaxf(-0.99999994f, u);
  return 1.41421356f * erfinv_xla(u);
}

// ---------------- Kernel 1: LMMSE prep (1 wave, Woodbury 16x16) ----------------
__global__ __launch_bounds__(64) void prep_kernel(const float* __restrict__ H,
                                                  const float* __restrict__ alpha,
                                                  char* __restrict__ ws) {
  float* m    = (float*)(ws + WS_M);
  float* EY   = (float*)(ws + WS_EY);
  float* gain = (float*)(ws + WS_GAIN);
  float* scal = (float*)(ws + WS_SCAL);
  float* Gws  = (float*)(ws + WS_G);

  __shared__ float sH[128 * 16];
  __shared__ float sC[16][16];
  __shared__ float sHC[128 * 16];
  __shared__ float sm[16];
  __shared__ double sHtH[16][16];
  __shared__ double M[16][33];
  __shared__ double dfac[16];
  __shared__ double spiv;
  __shared__ int   spivrow;
  __shared__ float sgain[16 * 128];

  int t = threadIdx.x;
  for (int i = t; i < 2048; i += 64) sH[i] = H[i];
  __syncthreads();

  if (t == 0) {
    float a0 = 0.0f;
    for (int j = 0; j < 16; ++j) a0 += alpha[j];
    scal[2] = a0;
    for (int j = 0; j < 16; ++j) { sm[j] = alpha[j] / a0; m[j] = sm[j]; }
  }
  __syncthreads();
  float a0 = scal[2];

  for (int e = t; e < 256; e += 64) {
    int i = e >> 4, j = e & 15;
    float v = ((i == j) ? sm[i] : 0.0f) - sm[i] * sm[j];
    sC[i][j] = v / (a0 + 1.0f);
  }
  for (int dd = t; dd < 128; dd += 64) {
    float acc = 0.0f;
    for (int j = 0; j < 16; ++j) acc += sH[dd * 16 + j] * sm[j];
    EY[dd] = acc;
  }
  __syncthreads();

  for (int idx = t; idx < 2048; idx += 64) {
    int dd = idx >> 4, j = idx & 15;
    float acc = 0.0f;
    for (int i = 0; i < 16; ++i) acc += sH[dd * 16 + i] * sC[i][j];
    sHC[idx] = acc;
  }
  for (int e = t; e < 256; e += 64) {
    int i = e >> 4, j = e & 15;
    double acc = 0.0;
    for (int dd = 0; dd < 128; ++dd)
      acc += (double)sH[dd * 16 + i] * (double)sH[dd * 16 + j];
    sHtH[i][j] = acc;
    Gws[i * 16 + j] = (float)acc;
  }
  __syncthreads();

  for (int e = t; e < 256; e += 64) {
    int i = e >> 4, j = e & 15;
    double acc = (i == j) ? 0.01 : 0.0;
    for (int k = 0; k < 16; ++k) acc += (double)sC[i][k] * sHtH[k][j];
    M[i][j] = acc;
    M[i][16 + j] = (i == j) ? 1.0 : 0.0;
  }
  __syncthreads();

  for (int p = 0; p < 16; ++p) {
    if (t == 0) {
      int best = p; double bv = fabs(M[p][p]);
      for (int r = p + 1; r < 16; ++r) {
        double v = fabs(M[r][p]);
        if (v > bv) { bv = v; best = r; }
      }
      spivrow = best;
    }
    __syncthreads();
    int pr = spivrow;
    double va = 0.0, vb = 0.0;
    if (t < 32 && pr != p) { va = M[p][t]; vb = M[pr][t]; }
    __syncthreads();
    if (t < 32 && pr != p) { M[p][t] = vb; M[pr][t] = va; }
    __syncthreads();
    if (t == 0) spiv = 1.0 / M[p][p];
    __syncthreads();
    if (t < 32) M[p][t] *= spiv;
    if (t < 16) dfac[t] = M[t][p];
    __syncthreads();
    for (int e = t; e < 512; e += 64) {
      int r = e >> 5, c = e & 31;
      if (r != p) M[r][c] -= dfac[r] * M[p][c];
    }
    __syncthreads();
  }

  for (int idx = t; idx < 2048; idx += 64) {
    int j = idx >> 7, dd = idx & 127;
    double acc = 0.0;
    for (int k = 0; k < 16; ++k) acc += M[j][16 + k] * (double)sHC[dd * 16 + k];
    float g = (float)acc;
    sgain[j * 128 + dd] = g;
    gain[j * 128 + dd] = g;
  }
  __syncthreads();

  if (t == 0) {
    float tr = 0.0f;
    for (int j = 0; j < 16; ++j) {
      float s2 = 0.0f;
      for (int dd = 0; dd < 128; ++dd) s2 += sgain[j * 128 + dd] * sHC[dd * 16 + j];
      tr += sC[j][j] - s2;
    }
    tr = fmaxf(tr, 0.0f) + 1e-6f;
    scal[0] = tr;
  }
}

// ---------------- Kernel 2: fused per-n prep + sampling + moments ----------------
// Phase 0: diri + u only (no lgamma — cn dropped via softmax shift-invariance;
// round-9/10 lesson: inlined lgammaf costs 28 VGPR = ~50us).
__global__ __launch_bounds__(256) void main_kernel(const float* __restrict__ y,
                                                   const float* __restrict__ Hg,
                                                   const float* __restrict__ alpha,
                                                   const char* __restrict__ ws,
                                                   float* __restrict__ out) {
  const float* mws  = (const float*)(ws + WS_M);
  const float* EYw  = (const float*)(ws + WS_EY);
  const float* gain = (const float*)(ws + WS_GAIN);
  const float* scal = (const float*)(ws + WS_SCAL);
  const float* Gw   = (const float*)(ws + WS_G);

  __shared__ float slg_all[32][256];   // lg for all chunks (32 KB); prologue aliases it
  __shared__ float sz[16][17];
  __shared__ float slw[16], swv[16];
  __shared__ float sdiri[16], su2[16], stv[16];
  __shared__ float sM, sS, sFac;

  int t = threadIdx.x;
  int n = blockIdx.x;
  int h_sub = t >> 4, j = t & 15;

  // ---- Phase 0: per-n proposal concentrations (tv/u dots; NO lgamma) ----
  {
    float* sGainT = &slg_all[0][0];      // [128][17]: gain transposed, padded
    float* sHs    = sGainT + 2176;       // [128][16]
    float* sys    = sHs + 2048;          // [128]
    float* sEYs   = sys + 128;           // [128]
    for (int i = t; i < 2048; i += 256) {
      sGainT[(i & 127) * 17 + (i >> 7)] = gain[i];   // stride-17: conflict-free
      sHs[i] = Hg[i];
    }
    if (t < 128) { sys[t] = y[n * 128 + t]; sEYs[t] = EYw[t]; }
    __syncthreads();
    if (t < 16) {
      float tv = mws[t];
      float u = 0.0f;
      for (int dd = 0; dd < 128; ++dd) {
        float yv = sys[dd];
        float dy = yv - sEYs[dd];
        tv += dy * sGainT[dd * 17 + t];
        u  += yv * sHs[dd * 16 + t];
      }
      stv[t] = tv;
      su2[t] = 2.0f * u;
    }
    __syncthreads();
    if (t == 0) {
      float s = 0.0f;
      for (int jj = 0; jj < 16; ++jj) {
        float v = fmaxf(stv[jj], 0.0f) + 1e-6f; stv[jj] = v; s += v;
      }
      float ssq = 0.0f;
      for (int jj = 0; jj < 16; ++jj) {
        float v = stv[jj] / s; stv[jj] = v; ssq += v * v;
      }
      float k = (1.0f - ssq) / scal[0] - 1.0f;
      for (int jj = 0; jj < 16; ++jj)
        sdiri[jj] = fmaxf(k * stv[jj], 0.0f) + 0.8f;
      sM = -INFINITY; sS = 0.0f; sFac = 1.0f;
    }
    __syncthreads();
  }

  float aj   = sdiri[j];
  float uj2  = su2[j];
  float admj = alpha[j] - aj;

  // ---- Phase 1: self-paced sampling (round-7 sampler + f32 erfinv log1p) ----
  {
    bool boost = (aj >= 1.0f);
    float aa = boost ? aj : (aj + 1.0f);
    float d  = aa - 0.33333334f;
    float cc = 0.33333334f / sqrtf(d);
    float inv_a = 1.0f / aj;
    float ld32 = logf(d);                    // loop-invariant (accept-path value)
    int numc = (h_sub < 4) ? 32 : 31;        // h = 16c+h_sub < 500
    int c = 0;
    bool need_init = true;
    bool pending = true;
    uint32_t kcx = 0, kcy = 0;
    float log_samples = 0.0f;

    while (__ballot(pending)) {
      if (pending) {
        if (need_init) {
          int h = c * 16 + h_sub;
          uint32_t jf = (((uint32_t)h * 2048u + (uint32_t)n) << 4) | (uint32_t)j;
          uint32_t ka, kb, ska, skb;
          tf_block(0u, 42u, 0u, jf, ka, kb);     // per-sample key (foldlike split)
          tf_block(ka, kb, 0u, 0u, kcx, kcy);    // carried key
          tf_block(ka, kb, 0u, 1u, ska, skb);    // subkey -> exponential
          float ef = u01(rb32(ska, skb));
          log_samples = log1pf(-ef);             // continuous -> f32
          need_init = false;
        }
        // one Marsaglia-Tsang outer iteration
        uint32_t xka, xkb, Uka, Ukb;
        tf_block(kcx, kcy, 0u, 1u, xka, xkb);    // x_key
        tf_block(kcx, kcy, 0u, 2u, Uka, Ukb);    // U_key
        float x = 0.0f, v = -1.0f;
        for (int in = 0; in < 256; ++in) {
          uint32_t sxa, sxb;
          tf_block(xka, xkb, 0u, 1u, sxa, sxb);  // subkey for normal
          x = normal_jax(sxa, sxb);
          v = 1.0f + x * cc;
          if (v > 0.0f) break;
          uint32_t nxa, nxb;
          tf_block(xka, xkb, 0u, 0u, nxa, nxb);  // lazy inner carry
          xka = nxa; xkb = nxb;
        }
        float X = x * x;
        float V = (v * v) * v;
        float U = u01(rb32(Uka, Ukb));
        float lv32 = logf(V);                    // test fast-path + accept output
        // continue while BOTH hold; accept when either fails.
        bool cont = (U >= 1.0f - 0.0331f * (X * X));
        if (cont) {
          // margin-gated log test: f32 fast path, f64 fallback at the boundary.
          float lu32  = logf(U);
          float rhs32 = X * 0.5f + d * ((1.0f - V) + lv32);
          float margin = lu32 - rhs32;
          float thr = 4.8e-7f * fabsf(lu32)
                    + 4.8e-7f * d * fabsf(lv32)
                    + 1.2e-7f * (fabsf(rhs32) + X)
                    + 1e-7f;
          if (fabsf(margin) > thr) {
            cont = (margin >= 0.0f);
          } else {
            cont = (flog(U) >= X * 0.5f + d * ((1.0f - V) + flog(V)));
          }
        }
        if (cont) {
          uint32_t kna, knb;
          tf_block(kcx, kcy, 0u, 0u, kna, knb);  // lazy outer carry
          kcx = kna; kcy = knb;
        } else {
          float log_boost = (boost || log_samples == 0.0f)
                              ? 0.0f : log_samples * inv_a;
          slg_all[c][t] = (ld32 + lv32) + log_boost;  // == (logf(d)+logf(V))+boost
          ++c;
          need_init = true;
          pending = (c < numc);
        }
      }
    }
  }

  // ---- Phase 2: softmax + importance weights + moment accumulation ----
  float Greg[16];
#pragma unroll
  for (int k = 0; k < 16; ++k) Greg[k] = Gw[j * 16 + k];
  __syncthreads();   // slg_all complete (sM init done in Phase 0)

  float acc = 0.0f;     // zzy[k=h_sub][l=j]
  float zyacc = 0.0f;   // threads t<16 own zy[t]

  for (int cch = 0; cch < 32; ++cch) {
    int h = cch * 16 + h_sub;
    bool valid = (h < NSAMP);
    float lg = slg_all[cch][t];

    // row softmax via intra-wave shuffles (row = 16 contiguous lanes)
    float mx = lg;
    mx = fmaxf(mx, __shfl_xor(mx, 1, 16));
    mx = fmaxf(mx, __shfl_xor(mx, 2, 16));
    mx = fmaxf(mx, __shfl_xor(mx, 4, 16));
    mx = fmaxf(mx, __shfl_xor(mx, 8, 16));
    float ez = expf(lg - mx);
    float se = ez;
    se += __shfl_xor(se, 1, 16);
    se += __shfl_xor(se, 2, 16);
    se += __shfl_xor(se, 4, 16);
    se += __shfl_xor(se, 8, 16);
    float z = valid ? (ez / se) : 0.0f;
    sz[h_sub][j] = z;                      // same-wave readers below
    float lz = logf(z);
    float pq = admj * lz;                  // p2 - q contribution

    // quadratic form: (Gz)_j then z_j*((Gz)_j - 2u_j)
    float gz = 0.0f;
#pragma unroll
    for (int k = 0; k < 16; ++k) gz = fmaf(Greg[k], sz[h_sub][k], gz);
    float sres = z * (gz - uj2);

    pq   += __shfl_xor(pq, 1, 16);
    pq   += __shfl_xor(pq, 2, 16);
    pq   += __shfl_xor(pq, 4, 16);
    pq   += __shfl_xor(pq, 8, 16);
    sres += __shfl_xor(sres, 1, 16);
    sres += __shfl_xor(sres, 2, 16);
    sres += __shfl_xor(sres, 4, 16);
    sres += __shfl_xor(sres, 8, 16);

    if (j == 0) {
      // per-n constant dropped: softmax over h is shift-invariant.
      float lw = -50.0f * sres + pq;
      slw[h_sub] = valid ? lw : -INFINITY;
    }
    __syncthreads();   // B1: slw + all rows' sz visible

    if (t < 16) {
      float cmax = sM;
      for (int hh = 0; hh < 16; ++hh) cmax = fmaxf(cmax, slw[hh]);
      float w = expf(slw[t] - cmax);
      swv[t] = w;
      if (t == 0) {
        float f2 = expf(sM - cmax);
        float Snew = sS * f2;
        for (int hh = 0; hh < 16; ++hh) Snew += swv[hh];
        sM = cmax; sS = Snew; sFac = f2;
      }
    }
    __syncthreads();   // B2: swv, sFac visible

    float fc = sFac;
    acc *= fc;
#pragma unroll
    for (int hh = 0; hh < 16; ++hh)
      acc = fmaf(swv[hh] * sz[hh][h_sub], sz[hh][j], acc);
    if (t < 16) {
      zyacc *= fc;
#pragma unroll
      for (int hh = 0; hh < 16; ++hh) zyacc = fmaf(swv[hh], sz[hh][t], zyacc);
    }
    __syncthreads();   // B3: protect sz from next chunk's overwrite
  }

  float Sf = sS;
  if (t < 16) out[n * 16 + t] = zyacc / Sf;
  out[N_OBS * R_DIM + n * 256 + t] = acc / Sf;
}

extern "C" void kernel_launch(void* const* d_in, const int* in_sizes, int n_in,
                              void* d_out, int out_size, void* d_ws, size_t ws_size,
                              hipStream_t stream) {
  const float* y     = (const float*)d_in[0];
  const float* H     = (const float*)d_in[1];
  const float* alpha = (const float*)d_in[2];
  char* ws = (char*)d_ws;
  float* out = (float*)d_out;

  prep_kernel<<<1, 64, 0, stream>>>(H, alpha, ws);
  main_kernel<<<N_OBS, 256, 0, stream>>>(y, H, alpha, ws, out);
}